// Round 4
// baseline (2518.060 us; speedup 1.0000x reference)
//
#include <hip/hip_runtime.h>

// FBSNN: 50-step SDE loop, two 2-64-64-1 MLPs (Q control, Y value + dY/dy tangent).
// R3: FUSED phase — Q(t1,y1) for next step computed together with Y(t1,y1) for this
// step (same eval point): 3 independent MFMA/epilogue streams per mt tile (~3x ILP),
// one LDS exchange per step instead of two. Layer-1 in packed fp16 (v_pk_fma_f16):
// halves VALU and removes all cvt repacking (pk results are the A-frag halves).

#define B_TOT 262144
#define NSTEPS 50
#define DT 0.01f
#define SIGMA 0.5f

typedef _Float16 half8_t __attribute__((ext_vector_type(8)));
typedef __fp16   fp16x2  __attribute__((ext_vector_type(2)));
typedef float    float4_t __attribute__((ext_vector_type(4)));

union H8 { half8_t v; fp16x2 p[4]; };

#define MFMA(a, b, c) __builtin_amdgcn_mfma_f32_16x16x32_f16((a), (b), (c), 0, 0, 0)

// v_add_f32 with DPP row_ror: full 16-lane row reduction on the VALU pipe.
template<int CTRL>
__device__ __forceinline__ float dpp_add(float x) {
    union { int i; float f; } u, o;
    u.f = x;
    o.i = __builtin_amdgcn_update_dpp(0, u.i, CTRL, 0xF, 0xF, true);
    return x + o.f;
}
__device__ __forceinline__ float row_reduce16(float x) {
    x = dpp_add<0x121>(x);  // row_ror:1
    x = dpp_add<0x122>(x);  // row_ror:2
    x = dpp_add<0x124>(x);  // row_ror:4
    x = dpp_add<0x128>(x);  // row_ror:8
    return x;
}

__global__ void zero_out_k(float* out) { out[0] = 0.f; }

__global__ __launch_bounds__(256, 3) void fbsnn_k(
    const float* __restrict__ dW,  const float* __restrict__ y0i,
    const float* __restrict__ Yw1, const float* __restrict__ Yb1,
    const float* __restrict__ Yw2, const float* __restrict__ Yb2,
    const float* __restrict__ Yw3, const float* __restrict__ Yb3,
    const float* __restrict__ Qw1, const float* __restrict__ Qb1,
    const float* __restrict__ Qw2, const float* __restrict__ Qb2,
    const float* __restrict__ Qw3, const float* __restrict__ Qb3,
    float* __restrict__ out)
{
    // W2 transposed: w2[n*72 + k] = W2[k*64 + n]; stride 72 keeps b128 aligned.
    __shared__ __align__(16) _Float16 w2q[64 * 72];
    __shared__ __align__(16) _Float16 w2y[64 * 72];
    // layer1 consts fp32: [0..63]=w1_t row, [64..127]=w1_y row, [128..191]=b1
    __shared__ __align__(16) float l1q[192];
    __shared__ __align__(16) float l1y[192];
    // per-wave sample-layout exchange buffers (q, Y, dY)
    __shared__ __align__(16) float xbA[4][64];
    __shared__ __align__(16) float xbB[4][64];
    __shared__ __align__(16) float xbC[4][64];
    __shared__ float rb[4];

    const int tid = threadIdx.x;

    #pragma unroll
    for (int it = 0; it < 16; ++it) {
        int e = it * 256 + tid;
        int k = e >> 6, n = e & 63;
        w2q[n * 72 + k] = (_Float16)Qw2[e];
        w2y[n * 72 + k] = (_Float16)Yw2[e];
    }
    if (tid < 64) {
        l1q[tid] = Qw1[tid]; l1q[64 + tid] = Qw1[64 + tid]; l1q[128 + tid] = Qb1[tid];
        l1y[tid] = Yw1[tid]; l1y[64 + tid] = Yw1[64 + tid]; l1y[128 + tid] = Yb1[tid];
    }
    __syncthreads();

    const int lane = tid & 63;
    const int wv   = tid >> 6;
    const int g    = lane >> 4;     // quad group 0..3
    const int c    = lane & 15;     // column within tile
    const int sG   = blockIdx.x * 256 + wv * 64 + lane;   // global sample
    const int k0   = g * 8;         // this lane's k-slice base

    // packed layer-1 y-row weights, held in regs for the whole loop
    // pair j: j<4 -> hidden (k0+2j, k0+2j+1); j>=4 -> hidden (32+k0+2(j-4), +1)
    fp16x2 wqh[8], wyh[8];
    #pragma unroll
    for (int j = 0; j < 8; ++j) {
        int idx = (j < 4) ? (k0 + 2 * j) : (32 + k0 + 2 * (j - 4));
        wqh[j] = fp16x2{(__fp16)l1q[64 + idx], (__fp16)l1q[64 + idx + 1]};
        wyh[j] = fp16x2{(__fp16)l1y[64 + idx], (__fp16)l1y[64 + idx + 1]};
    }

    // per-lane resident epilogue constants (n = c + 16*nt)
    float qb2[4], qw3[4], yb2[4], yw3[4];
    #pragma unroll
    for (int nt = 0; nt < 4; ++nt) {
        qb2[nt] = Qb2[c + 16 * nt]; qw3[nt] = Qw3[c + 16 * nt];
        yb2[nt] = Yb2[c + 16 * nt]; yw3[nt] = Yw3[c + 16 * nt];
    }
    const float qb3 = Qb3[0], yb3 = Yb3[0];

    const fp16x2 zero2 = {(__fp16)0.f, (__fp16)0.f};
    const fp16x2 one2  = {(__fp16)1.f, (__fp16)1.f};
    const fp16x2 big2  = {(__fp16)32768.f, (__fp16)32768.f};

    float* xA = xbA[wv];
    float* xB = xbB[wv];
    float* xC = xbC[wv];

    // ---- fused eval of BOTH nets at (tt, yy): q = Q-MLP, Y/dY = Y-MLP fwd+tangent ----
    auto feval = [&](float tt, float yy, float& qo, float& Yo, float& dYo) {
        // a-build fp32 from LDS, then pack to fp16x2
        float aq[16], ay[16];
        #pragma unroll
        for (int h = 0; h < 2; ++h) {
            int kk = k0 + 32 * h;
            float4_t qt0 = *(const float4_t*)&l1q[kk];
            float4_t qt1 = *(const float4_t*)&l1q[kk + 4];
            float4_t qc0 = *(const float4_t*)&l1q[128 + kk];
            float4_t qc1 = *(const float4_t*)&l1q[128 + kk + 4];
            float4_t yt0 = *(const float4_t*)&l1y[kk];
            float4_t yt1 = *(const float4_t*)&l1y[kk + 4];
            float4_t yc0 = *(const float4_t*)&l1y[128 + kk];
            float4_t yc1 = *(const float4_t*)&l1y[128 + kk + 4];
            #pragma unroll
            for (int j = 0; j < 4; ++j) {
                aq[8 * h + j]     = fmaf(tt, qt0[j], qc0[j]);
                aq[8 * h + 4 + j] = fmaf(tt, qt1[j], qc1[j]);
                ay[8 * h + j]     = fmaf(tt, yt0[j], yc0[j]);
                ay[8 * h + 4 + j] = fmaf(tt, yt1[j], yc1[j]);
            }
        }
        fp16x2 aqh[8], ayh[8];
        #pragma unroll
        for (int j = 0; j < 8; ++j) {
            aqh[j] = __builtin_amdgcn_cvt_pkrtz(aq[2 * j], aq[2 * j + 1]);
            ayh[j] = __builtin_amdgcn_cvt_pkrtz(ay[2 * j], ay[2 * j + 1]);
        }

        #pragma unroll
        for (int mt = 0; mt < 4; ++mt) {
            float ym = __shfl(yy, mt * 16 + c, 64);
            fp16x2 ym2 = __builtin_amdgcn_cvt_pkrtz(ym, ym);

            H8 qa0, qa1, yf0, yf1, yt0f, yt1f;
            #pragma unroll
            for (int j = 0; j < 8; ++j) {
                fp16x2 hq = __builtin_elementwise_max((fp16x2)(wqh[j] * ym2 + aqh[j]), zero2);
                fp16x2 hy = __builtin_elementwise_max((fp16x2)(wyh[j] * ym2 + ayh[j]), zero2);
                // ReLU' mask: 1 for hy>~3e-5, 0 for hy==0 (boundary error negligible)
                fp16x2 mk = __builtin_elementwise_min((fp16x2)(hy * big2), one2);
                fp16x2 td = mk * wyh[j];
                if (j < 4) { qa0.p[j] = hq;     yf0.p[j] = hy;     yt0f.p[j] = td; }
                else       { qa1.p[j - 4] = hq; yf1.p[j - 4] = hy; yt1f.p[j - 4] = td; }
            }

            float4_t cq[4] = {}, cf[4] = {}, ct[4] = {};
            #pragma unroll
            for (int nt = 0; nt < 4; ++nt) {
                const _Float16* bq = &w2q[(c + 16 * nt) * 72 + k0];
                const _Float16* by = &w2y[(c + 16 * nt) * 72 + k0];
                half8_t bq0 = *(const half8_t*)bq;
                half8_t bq1 = *(const half8_t*)(bq + 32);
                half8_t by0 = *(const half8_t*)by;
                half8_t by1 = *(const half8_t*)(by + 32);
                cq[nt] = MFMA(qa0.v, bq0, cq[nt]);
                cq[nt] = MFMA(qa1.v, bq1, cq[nt]);
                cf[nt] = MFMA(yf0.v, by0, cf[nt]);
                cf[nt] = MFMA(yf1.v, by1, cf[nt]);
                ct[nt] = MFMA(yt0f.v, by0, ct[nt]);
                ct[nt] = MFMA(yt1f.v, by1, ct[nt]);
            }

            float pq[4] = {0, 0, 0, 0}, pf[4] = {0, 0, 0, 0}, pd[4] = {0, 0, 0, 0};
            #pragma unroll
            for (int nt = 0; nt < 4; ++nt) {
                #pragma unroll
                for (int r = 0; r < 4; ++r) {
                    float vq = fmaxf(cq[nt][r] + qb2[nt], 0.f);
                    pq[r] = fmaf(vq, qw3[nt], pq[r]);
                    float pre = cf[nt][r] + yb2[nt];
                    pf[r] = fmaf(fmaxf(pre, 0.f), yw3[nt], pf[r]);
                    float dd = (pre > 0.f) ? ct[nt][r] : 0.f;
                    pd[r] = fmaf(dd, yw3[nt], pd[r]);
                }
            }
            #pragma unroll
            for (int r = 0; r < 4; ++r) {
                pq[r] = row_reduce16(pq[r]);
                pf[r] = row_reduce16(pf[r]);
                pd[r] = row_reduce16(pd[r]);
            }
            if (c == 0) {
                float4_t q4, f4, d4;
                #pragma unroll
                for (int r = 0; r < 4; ++r) {
                    q4[r] = pq[r] + qb3; f4[r] = pf[r] + yb3; d4[r] = pd[r];
                }
                *(float4_t*)&xA[mt * 16 + g * 4] = q4;
                *(float4_t*)&xB[mt * 16 + g * 4] = f4;
                *(float4_t*)&xC[mt * 16 + g * 4] = d4;
            }
        }
        qo  = xA[lane];
        Yo  = xB[lane];
        dYo = xC[lane];
    };

    float y = y0i[0];
    float t = 0.f;
    float q0, Y0, dY0, loss = 0.f;
    feval(0.f, y, q0, Y0, dY0);

    float dw = dW[sG];  // prefetched for step 0
    for (int s = 0; s < NSTEPS; ++s) {
        int sn = (s + 1 < NSTEPS) ? (s + 1) : (NSTEPS - 1);
        float dw_next = dW[(size_t)sn * B_TOT + sG];

        float y1 = fmaf(SIGMA, dw, fmaf(q0, DT, y));
        float t1 = t + DT;

        float q1, Y1, dY1;
        feval(t1, y1, q1, Y1, dY1);

        // resid = Y1 - (Y0 - 0.5*q0^2*DT + SIGMA*dY0*dw)
        float resid = Y1 - (Y0 - 0.5f * q0 * q0 * DT + SIGMA * dY0 * dw);
        loss = fmaf(resid, resid, loss);

        y = y1; t = t1; q0 = q1; Y0 = Y1; dY0 = dY1; dw = dw_next;
    }

    // terminal: (YN - yN^2)^2
    float tm = Y0 - y * y;
    loss = fmaf(tm, tm, loss);

    #pragma unroll
    for (int off = 1; off < 64; off <<= 1) loss += __shfl_xor(loss, off, 64);
    if (lane == 0) rb[wv] = loss;
    __syncthreads();
    if (tid == 0) atomicAdd(out, (rb[0] + rb[1] + rb[2] + rb[3]) * (1.0f / (float)B_TOT));
}

extern "C" void kernel_launch(void* const* d_in, const int* in_sizes, int n_in,
                              void* d_out, int out_size, void* d_ws, size_t ws_size,
                              hipStream_t stream) {
    const float* dW  = (const float*)d_in[0];
    const float* y0i = (const float*)d_in[1];
    const float* Yw1 = (const float*)d_in[2];
    const float* Yb1 = (const float*)d_in[3];
    const float* Yw2 = (const float*)d_in[4];
    const float* Yb2 = (const float*)d_in[5];
    const float* Yw3 = (const float*)d_in[6];
    const float* Yb3 = (const float*)d_in[7];
    const float* Qw1 = (const float*)d_in[8];
    const float* Qb1 = (const float*)d_in[9];
    const float* Qw2 = (const float*)d_in[10];
    const float* Qb2 = (const float*)d_in[11];
    const float* Qw3 = (const float*)d_in[12];
    const float* Qb3 = (const float*)d_in[13];
    float* out = (float*)d_out;

    hipLaunchKernelGGL(zero_out_k, dim3(1), dim3(1), 0, stream, out);
    hipLaunchKernelGGL(fbsnn_k, dim3(B_TOT / 256), dim3(256), 0, stream,
                       dW, y0i, Yw1, Yb1, Yw2, Yb2, Yw3, Yb3,
                       Qw1, Qb1, Qw2, Qb2, Qw3, Qb3, out);
}

// Round 5
// 1397.022 us; speedup vs baseline: 1.8024x; 1.8024x over previous
//
#include <hip/hip_runtime.h>

// FBSNN: 50-step SDE loop, two 2-64-64-1 MLPs (Q control, Y value + dY/dy tangent).
// R4 regression root-cause: big feval lambda with 2 call sites went to scratch
// (VGPR 84, FETCH 5.4 GB). R5: SINGLE call site, body textually inline, no lambda;
// step loop runs NSTEPS+1 times (resid computed against previous iteration's state).
// Keeps R4's fused Q/Y/tangent 3-stream MFMA + packed-fp16 layer 1.

#define B_TOT 262144
#define NSTEPS 50
#define DT 0.01f
#define SIGMA 0.5f

typedef _Float16 half8_t __attribute__((ext_vector_type(8)));
typedef __fp16   fp16x2  __attribute__((ext_vector_type(2)));
typedef float    float4_t __attribute__((ext_vector_type(4)));

union H8 { half8_t v; fp16x2 p[4]; };

#define MFMA(a, b, c) __builtin_amdgcn_mfma_f32_16x16x32_f16((a), (b), (c), 0, 0, 0)

// v_add_f32 with DPP row_ror: full 16-lane row reduction on the VALU pipe.
template<int CTRL>
__device__ __forceinline__ float dpp_add(float x) {
    union { int i; float f; } u, o;
    u.f = x;
    o.i = __builtin_amdgcn_update_dpp(0, u.i, CTRL, 0xF, 0xF, true);
    return x + o.f;
}
__device__ __forceinline__ float row_reduce16(float x) {
    x = dpp_add<0x121>(x);  // row_ror:1
    x = dpp_add<0x122>(x);  // row_ror:2
    x = dpp_add<0x124>(x);  // row_ror:4
    x = dpp_add<0x128>(x);  // row_ror:8
    return x;
}

__global__ void zero_out_k(float* out) { out[0] = 0.f; }

__global__ __launch_bounds__(256, 3) void fbsnn_k(
    const float* __restrict__ dW,  const float* __restrict__ y0i,
    const float* __restrict__ Yw1, const float* __restrict__ Yb1,
    const float* __restrict__ Yw2, const float* __restrict__ Yb2,
    const float* __restrict__ Yw3, const float* __restrict__ Yb3,
    const float* __restrict__ Qw1, const float* __restrict__ Qb1,
    const float* __restrict__ Qw2, const float* __restrict__ Qb2,
    const float* __restrict__ Qw3, const float* __restrict__ Qb3,
    float* __restrict__ out)
{
    // W2 transposed: w2[n*72 + k] = W2[k*64 + n]; stride 72 keeps b128 aligned.
    __shared__ __align__(16) _Float16 w2q[64 * 72];
    __shared__ __align__(16) _Float16 w2y[64 * 72];
    // layer1 consts fp32: [0..63]=w1_t row, [64..127]=w1_y row, [128..191]=b1
    __shared__ __align__(16) float l1q[192];
    __shared__ __align__(16) float l1y[192];
    // per-wave sample-layout exchange buffers (q, Y, dY)
    __shared__ __align__(16) float xbA[4][64];
    __shared__ __align__(16) float xbB[4][64];
    __shared__ __align__(16) float xbC[4][64];
    __shared__ float rb[4];

    const int tid = threadIdx.x;

    #pragma unroll
    for (int it = 0; it < 16; ++it) {
        int e = it * 256 + tid;
        int k = e >> 6, n = e & 63;
        w2q[n * 72 + k] = (_Float16)Qw2[e];
        w2y[n * 72 + k] = (_Float16)Yw2[e];
    }
    if (tid < 64) {
        l1q[tid] = Qw1[tid]; l1q[64 + tid] = Qw1[64 + tid]; l1q[128 + tid] = Qb1[tid];
        l1y[tid] = Yw1[tid]; l1y[64 + tid] = Yw1[64 + tid]; l1y[128 + tid] = Yb1[tid];
    }
    __syncthreads();

    const int lane = tid & 63;
    const int wv   = tid >> 6;
    const int g    = lane >> 4;     // quad group 0..3
    const int c    = lane & 15;     // column within tile
    const int sG   = blockIdx.x * 256 + wv * 64 + lane;   // global sample
    const int k0   = g * 8;         // this lane's k-slice base

    // packed layer-1 y-row weights, held in regs for the whole loop
    fp16x2 wqh[8], wyh[8];
    #pragma unroll
    for (int j = 0; j < 8; ++j) {
        int idx = (j < 4) ? (k0 + 2 * j) : (32 + k0 + 2 * (j - 4));
        wqh[j] = fp16x2{(__fp16)l1q[64 + idx], (__fp16)l1q[64 + idx + 1]};
        wyh[j] = fp16x2{(__fp16)l1y[64 + idx], (__fp16)l1y[64 + idx + 1]};
    }

    // per-lane resident epilogue constants (n = c + 16*nt)
    float qb2[4], qw3[4], yb2[4], yw3[4];
    #pragma unroll
    for (int nt = 0; nt < 4; ++nt) {
        qb2[nt] = Qb2[c + 16 * nt]; qw3[nt] = Qw3[c + 16 * nt];
        yb2[nt] = Yb2[c + 16 * nt]; yw3[nt] = Yw3[c + 16 * nt];
    }
    const float qb3 = Qb3[0], yb3 = Yb3[0];

    const fp16x2 zero2 = {(__fp16)0.f, (__fp16)0.f};
    const fp16x2 one2  = {(__fp16)1.f, (__fp16)1.f};
    const fp16x2 big2  = {(__fp16)32768.f, (__fp16)32768.f};

    float* xA = xbA[wv];
    float* xB = xbB[wv];
    float* xC = xbC[wv];

    float y = y0i[0];
    float t = 0.f;
    float q0 = 0.f, Y0 = 0.f, dY0 = 0.f, dwprev = 0.f, loss = 0.f;
    float dw_next = dW[sG];

    // NSTEPS+1 fused evals, ONE call site (keeps the big body in registers).
    #pragma unroll 1
    for (int it = 0; it <= NSTEPS; ++it) {
        float dw = dw_next;
        int sn = (it < NSTEPS - 1) ? (it + 1) : (NSTEPS - 1);
        dw_next = dW[(size_t)sn * B_TOT + sG];

        // ======== fused eval of BOTH nets at (t, y) -> q, Y, dY ========
        float q, Y, dY;
        {
            float aq[16], ay[16];
            #pragma unroll
            for (int h = 0; h < 2; ++h) {
                int kk = k0 + 32 * h;
                float4_t qt0 = *(const float4_t*)&l1q[kk];
                float4_t qt1 = *(const float4_t*)&l1q[kk + 4];
                float4_t qc0 = *(const float4_t*)&l1q[128 + kk];
                float4_t qc1 = *(const float4_t*)&l1q[128 + kk + 4];
                float4_t yt0 = *(const float4_t*)&l1y[kk];
                float4_t yt1 = *(const float4_t*)&l1y[kk + 4];
                float4_t yc0 = *(const float4_t*)&l1y[128 + kk];
                float4_t yc1 = *(const float4_t*)&l1y[128 + kk + 4];
                #pragma unroll
                for (int j = 0; j < 4; ++j) {
                    aq[8 * h + j]     = fmaf(t, qt0[j], qc0[j]);
                    aq[8 * h + 4 + j] = fmaf(t, qt1[j], qc1[j]);
                    ay[8 * h + j]     = fmaf(t, yt0[j], yc0[j]);
                    ay[8 * h + 4 + j] = fmaf(t, yt1[j], yc1[j]);
                }
            }
            fp16x2 aqh[8], ayh[8];
            #pragma unroll
            for (int j = 0; j < 8; ++j) {
                aqh[j] = __builtin_amdgcn_cvt_pkrtz(aq[2 * j], aq[2 * j + 1]);
                ayh[j] = __builtin_amdgcn_cvt_pkrtz(ay[2 * j], ay[2 * j + 1]);
            }

            #pragma unroll
            for (int mt = 0; mt < 4; ++mt) {
                float ym = __shfl(y, mt * 16 + c, 64);
                fp16x2 ym2 = __builtin_amdgcn_cvt_pkrtz(ym, ym);

                H8 qa0, qa1, yf0, yf1, yt0f, yt1f;
                #pragma unroll
                for (int j = 0; j < 8; ++j) {
                    fp16x2 hq = __builtin_elementwise_max((fp16x2)(wqh[j] * ym2 + aqh[j]), zero2);
                    fp16x2 hy = __builtin_elementwise_max((fp16x2)(wyh[j] * ym2 + ayh[j]), zero2);
                    fp16x2 mk = __builtin_elementwise_min((fp16x2)(hy * big2), one2);
                    fp16x2 td = mk * wyh[j];
                    if (j < 4) { qa0.p[j] = hq;     yf0.p[j] = hy;     yt0f.p[j] = td; }
                    else       { qa1.p[j - 4] = hq; yf1.p[j - 4] = hy; yt1f.p[j - 4] = td; }
                }

                float4_t cq[4] = {}, cf[4] = {}, ct[4] = {};
                #pragma unroll
                for (int nt = 0; nt < 4; ++nt) {
                    const _Float16* bq = &w2q[(c + 16 * nt) * 72 + k0];
                    const _Float16* by = &w2y[(c + 16 * nt) * 72 + k0];
                    half8_t bq0 = *(const half8_t*)bq;
                    half8_t bq1 = *(const half8_t*)(bq + 32);
                    half8_t by0 = *(const half8_t*)by;
                    half8_t by1 = *(const half8_t*)(by + 32);
                    cq[nt] = MFMA(qa0.v, bq0, cq[nt]);
                    cq[nt] = MFMA(qa1.v, bq1, cq[nt]);
                    cf[nt] = MFMA(yf0.v, by0, cf[nt]);
                    cf[nt] = MFMA(yf1.v, by1, cf[nt]);
                    ct[nt] = MFMA(yt0f.v, by0, ct[nt]);
                    ct[nt] = MFMA(yt1f.v, by1, ct[nt]);
                }

                float pq[4] = {0, 0, 0, 0}, pf[4] = {0, 0, 0, 0}, pd[4] = {0, 0, 0, 0};
                #pragma unroll
                for (int nt = 0; nt < 4; ++nt) {
                    #pragma unroll
                    for (int r = 0; r < 4; ++r) {
                        float vq = fmaxf(cq[nt][r] + qb2[nt], 0.f);
                        pq[r] = fmaf(vq, qw3[nt], pq[r]);
                        float pre = cf[nt][r] + yb2[nt];
                        pf[r] = fmaf(fmaxf(pre, 0.f), yw3[nt], pf[r]);
                        float dd = (pre > 0.f) ? ct[nt][r] : 0.f;
                        pd[r] = fmaf(dd, yw3[nt], pd[r]);
                    }
                }
                #pragma unroll
                for (int r = 0; r < 4; ++r) {
                    pq[r] = row_reduce16(pq[r]);
                    pf[r] = row_reduce16(pf[r]);
                    pd[r] = row_reduce16(pd[r]);
                }
                if (c == 0) {
                    float4_t q4, f4, d4;
                    #pragma unroll
                    for (int r = 0; r < 4; ++r) {
                        q4[r] = pq[r] + qb3; f4[r] = pf[r] + yb3; d4[r] = pd[r];
                    }
                    *(float4_t*)&xA[mt * 16 + g * 4] = q4;
                    *(float4_t*)&xB[mt * 16 + g * 4] = f4;
                    *(float4_t*)&xC[mt * 16 + g * 4] = d4;
                }
            }
            q  = xA[lane];
            Y  = xB[lane];
            dY = xC[lane];
        }
        // ======== end fused eval ========

        if (it > 0) {
            float resid = Y - (Y0 - 0.5f * q0 * q0 * DT + SIGMA * dY0 * dwprev);
            loss = fmaf(resid, resid, loss);
        }
        q0 = q; Y0 = Y; dY0 = dY; dwprev = dw;

        if (it < NSTEPS) {
            y = fmaf(SIGMA, dw, fmaf(q, DT, y));
            t += DT;
        }
    }

    // terminal: (YN - yN^2)^2
    float tm = Y0 - y * y;
    loss = fmaf(tm, tm, loss);

    #pragma unroll
    for (int off = 1; off < 64; off <<= 1) loss += __shfl_xor(loss, off, 64);
    if (lane == 0) rb[wv] = loss;
    __syncthreads();
    if (tid == 0) atomicAdd(out, (rb[0] + rb[1] + rb[2] + rb[3]) * (1.0f / (float)B_TOT));
}

extern "C" void kernel_launch(void* const* d_in, const int* in_sizes, int n_in,
                              void* d_out, int out_size, void* d_ws, size_t ws_size,
                              hipStream_t stream) {
    const float* dW  = (const float*)d_in[0];
    const float* y0i = (const float*)d_in[1];
    const float* Yw1 = (const float*)d_in[2];
    const float* Yb1 = (const float*)d_in[3];
    const float* Yw2 = (const float*)d_in[4];
    const float* Yb2 = (const float*)d_in[5];
    const float* Yw3 = (const float*)d_in[6];
    const float* Yb3 = (const float*)d_in[7];
    const float* Qw1 = (const float*)d_in[8];
    const float* Qb1 = (const float*)d_in[9];
    const float* Qw2 = (const float*)d_in[10];
    const float* Qb2 = (const float*)d_in[11];
    const float* Qw3 = (const float*)d_in[12];
    const float* Qb3 = (const float*)d_in[13];
    float* out = (float*)d_out;

    hipLaunchKernelGGL(zero_out_k, dim3(1), dim3(1), 0, stream, out);
    hipLaunchKernelGGL(fbsnn_k, dim3(B_TOT / 256), dim3(256), 0, stream,
                       dW, y0i, Yw1, Yb1, Yw2, Yb2, Yw3, Yb3,
                       Qw1, Qb1, Qw2, Qb2, Qw3, Qb3, out);
}

// Round 6
// 784.636 us; speedup vs baseline: 3.2092x; 1.7805x over previous
//
#include <hip/hip_runtime.h>

// FBSNN: 50-step SDE loop, two 2-64-64-1 MLPs (Q control, Y value + dY/dy tangent).
// R5 root-cause: __launch_bounds__(256,3) VGPR cap (170) < fused-body demand -> scratch
// (VGPR 84, FETCH 2.2GB). R6: plain launch_bounds; per-nt fold of layer-3 (peak live
// accums 48->12 regs); bit_cast packing instead of union (SROA-clean).

#define B_TOT 262144
#define NSTEPS 50
#define DT 0.01f
#define SIGMA 0.5f

typedef _Float16 half8_t  __attribute__((ext_vector_type(8)));
typedef __fp16   fp16x2   __attribute__((ext_vector_type(2)));
typedef float    float4_t __attribute__((ext_vector_type(4)));
typedef int      int4_t   __attribute__((ext_vector_type(4)));

#define MFMA(a, b, c) __builtin_amdgcn_mfma_f32_16x16x32_f16((a), (b), (c), 0, 0, 0)

__device__ __forceinline__ half8_t pack4(fp16x2 a, fp16x2 b, fp16x2 c, fp16x2 d) {
    int4_t t;
    t[0] = __builtin_bit_cast(int, a);
    t[1] = __builtin_bit_cast(int, b);
    t[2] = __builtin_bit_cast(int, c);
    t[3] = __builtin_bit_cast(int, d);
    return __builtin_bit_cast(half8_t, t);
}

// v_add_f32 with DPP row_ror: full 16-lane row reduction on the VALU pipe.
template<int CTRL>
__device__ __forceinline__ float dpp_add(float x) {
    union { int i; float f; } u, o;
    u.f = x;
    o.i = __builtin_amdgcn_update_dpp(0, u.i, CTRL, 0xF, 0xF, true);
    return x + o.f;
}
__device__ __forceinline__ float row_reduce16(float x) {
    x = dpp_add<0x121>(x);  // row_ror:1
    x = dpp_add<0x122>(x);  // row_ror:2
    x = dpp_add<0x124>(x);  // row_ror:4
    x = dpp_add<0x128>(x);  // row_ror:8
    return x;
}

__global__ void zero_out_k(float* out) { out[0] = 0.f; }

__global__ __launch_bounds__(256) void fbsnn_k(
    const float* __restrict__ dW,  const float* __restrict__ y0i,
    const float* __restrict__ Yw1, const float* __restrict__ Yb1,
    const float* __restrict__ Yw2, const float* __restrict__ Yb2,
    const float* __restrict__ Yw3, const float* __restrict__ Yb3,
    const float* __restrict__ Qw1, const float* __restrict__ Qb1,
    const float* __restrict__ Qw2, const float* __restrict__ Qb2,
    const float* __restrict__ Qw3, const float* __restrict__ Qb3,
    float* __restrict__ out)
{
    // W2 transposed: w2[n*72 + k] = W2[k*64 + n]; stride 72 keeps b128 aligned.
    __shared__ __align__(16) _Float16 w2q[64 * 72];
    __shared__ __align__(16) _Float16 w2y[64 * 72];
    // layer1 consts fp32: [0..63]=w1_t row, [64..127]=w1_y row, [128..191]=b1
    __shared__ __align__(16) float l1q[192];
    __shared__ __align__(16) float l1y[192];
    // per-wave sample-layout exchange buffers (q, Y, dY)
    __shared__ __align__(16) float xbA[4][64];
    __shared__ __align__(16) float xbB[4][64];
    __shared__ __align__(16) float xbC[4][64];
    __shared__ float rb[4];

    const int tid = threadIdx.x;

    #pragma unroll
    for (int it = 0; it < 16; ++it) {
        int e = it * 256 + tid;
        int k = e >> 6, n = e & 63;
        w2q[n * 72 + k] = (_Float16)Qw2[e];
        w2y[n * 72 + k] = (_Float16)Yw2[e];
    }
    if (tid < 64) {
        l1q[tid] = Qw1[tid]; l1q[64 + tid] = Qw1[64 + tid]; l1q[128 + tid] = Qb1[tid];
        l1y[tid] = Yw1[tid]; l1y[64 + tid] = Yw1[64 + tid]; l1y[128 + tid] = Yb1[tid];
    }
    __syncthreads();

    const int lane = tid & 63;
    const int wv   = tid >> 6;
    const int g    = lane >> 4;     // quad group 0..3
    const int c    = lane & 15;     // column within tile
    const int sG   = blockIdx.x * 256 + wv * 64 + lane;   // global sample
    const int k0   = g * 8;         // this lane's k-slice base

    // packed layer-1 y-row weights, held in regs for the whole loop
    fp16x2 wqh[8], wyh[8];
    #pragma unroll
    for (int j = 0; j < 8; ++j) {
        int idx = (j < 4) ? (k0 + 2 * j) : (32 + k0 + 2 * (j - 4));
        wqh[j] = fp16x2{(__fp16)l1q[64 + idx], (__fp16)l1q[64 + idx + 1]};
        wyh[j] = fp16x2{(__fp16)l1y[64 + idx], (__fp16)l1y[64 + idx + 1]};
    }

    // per-lane resident epilogue constants (n = c + 16*nt)
    float qb2[4], qw3[4], yb2[4], yw3[4];
    #pragma unroll
    for (int nt = 0; nt < 4; ++nt) {
        qb2[nt] = Qb2[c + 16 * nt]; qw3[nt] = Qw3[c + 16 * nt];
        yb2[nt] = Yb2[c + 16 * nt]; yw3[nt] = Yw3[c + 16 * nt];
    }
    const float qb3 = Qb3[0], yb3 = Yb3[0];

    const fp16x2 zero2 = {(__fp16)0.f, (__fp16)0.f};
    const fp16x2 one2  = {(__fp16)1.f, (__fp16)1.f};
    const fp16x2 big2  = {(__fp16)32768.f, (__fp16)32768.f};

    float* xA = xbA[wv];
    float* xB = xbB[wv];
    float* xC = xbC[wv];

    float y = y0i[0];
    float t = 0.f;
    float q0 = 0.f, Y0 = 0.f, dY0 = 0.f, dwprev = 0.f, loss = 0.f;
    float dw_next = dW[sG];

    // NSTEPS+1 fused evals, ONE call site.
    #pragma unroll 1
    for (int it = 0; it <= NSTEPS; ++it) {
        float dw = dw_next;
        int sn = (it < NSTEPS - 1) ? (it + 1) : (NSTEPS - 1);
        dw_next = dW[(size_t)sn * B_TOT + sG];

        // ======== fused eval of BOTH nets at (t, y) -> q, Y, dY ========
        float q, Y, dY;
        {
            // a-vector (t-dependent part of layer 1), packed fp16
            fp16x2 aqh[8], ayh[8];
            #pragma unroll
            for (int h = 0; h < 2; ++h) {
                int kk = k0 + 32 * h;
                float4_t qt0 = *(const float4_t*)&l1q[kk];
                float4_t qt1 = *(const float4_t*)&l1q[kk + 4];
                float4_t qc0 = *(const float4_t*)&l1q[128 + kk];
                float4_t qc1 = *(const float4_t*)&l1q[128 + kk + 4];
                float4_t yt0 = *(const float4_t*)&l1y[kk];
                float4_t yt1 = *(const float4_t*)&l1y[kk + 4];
                float4_t yc0 = *(const float4_t*)&l1y[128 + kk];
                float4_t yc1 = *(const float4_t*)&l1y[128 + kk + 4];
                #pragma unroll
                for (int j = 0; j < 2; ++j) {
                    float a0 = fmaf(t, qt0[2 * j], qc0[2 * j]);
                    float a1 = fmaf(t, qt0[2 * j + 1], qc0[2 * j + 1]);
                    float a2 = fmaf(t, qt1[2 * j], qc1[2 * j]);
                    float a3 = fmaf(t, qt1[2 * j + 1], qc1[2 * j + 1]);
                    aqh[4 * h + j]     = __builtin_amdgcn_cvt_pkrtz(a0, a1);
                    aqh[4 * h + 2 + j] = __builtin_amdgcn_cvt_pkrtz(a2, a3);
                    float b0 = fmaf(t, yt0[2 * j], yc0[2 * j]);
                    float b1 = fmaf(t, yt0[2 * j + 1], yc0[2 * j + 1]);
                    float b2 = fmaf(t, yt1[2 * j], yc1[2 * j]);
                    float b3 = fmaf(t, yt1[2 * j + 1], yc1[2 * j + 1]);
                    ayh[4 * h + j]     = __builtin_amdgcn_cvt_pkrtz(b0, b1);
                    ayh[4 * h + 2 + j] = __builtin_amdgcn_cvt_pkrtz(b2, b3);
                }
            }

            #pragma unroll
            for (int mt = 0; mt < 4; ++mt) {
                float ym = __shfl(y, mt * 16 + c, 64);
                fp16x2 ym2 = __builtin_amdgcn_cvt_pkrtz(ym, ym);

                fp16x2 hqa[8], hya[8], tda[8];
                #pragma unroll
                for (int j = 0; j < 8; ++j) {
                    hqa[j] = __builtin_elementwise_max((fp16x2)(wqh[j] * ym2 + aqh[j]), zero2);
                    fp16x2 hy = __builtin_elementwise_max((fp16x2)(wyh[j] * ym2 + ayh[j]), zero2);
                    hya[j] = hy;
                    fp16x2 mk = __builtin_elementwise_min((fp16x2)(hy * big2), one2);
                    tda[j] = mk * wyh[j];
                }
                half8_t qa_lo = pack4(hqa[0], hqa[1], hqa[2], hqa[3]);
                half8_t qa_hi = pack4(hqa[4], hqa[5], hqa[6], hqa[7]);
                half8_t yf_lo = pack4(hya[0], hya[1], hya[2], hya[3]);
                half8_t yf_hi = pack4(hya[4], hya[5], hya[6], hya[7]);
                half8_t yt_lo = pack4(tda[0], tda[1], tda[2], tda[3]);
                half8_t yt_hi = pack4(tda[4], tda[5], tda[6], tda[7]);

                float pq[4] = {0, 0, 0, 0}, pf[4] = {0, 0, 0, 0}, pd[4] = {0, 0, 0, 0};
                #pragma unroll
                for (int nt = 0; nt < 4; ++nt) {
                    const _Float16* bq = &w2q[(c + 16 * nt) * 72 + k0];
                    const _Float16* by = &w2y[(c + 16 * nt) * 72 + k0];
                    half8_t bq0 = *(const half8_t*)bq;
                    half8_t bq1 = *(const half8_t*)(bq + 32);
                    half8_t by0 = *(const half8_t*)by;
                    half8_t by1 = *(const half8_t*)(by + 32);
                    float4_t cq = {}, cf = {}, ct = {};
                    cq = MFMA(qa_lo, bq0, cq);
                    cq = MFMA(qa_hi, bq1, cq);
                    cf = MFMA(yf_lo, by0, cf);
                    cf = MFMA(yf_hi, by1, cf);
                    ct = MFMA(yt_lo, by0, ct);
                    ct = MFMA(yt_hi, by1, ct);
                    // fold layer-3 for this nt immediately (keeps live accums at 12)
                    #pragma unroll
                    for (int r = 0; r < 4; ++r) {
                        float vq = fmaxf(cq[r] + qb2[nt], 0.f);
                        pq[r] = fmaf(vq, qw3[nt], pq[r]);
                        float pre = cf[r] + yb2[nt];
                        pf[r] = fmaf(fmaxf(pre, 0.f), yw3[nt], pf[r]);
                        float dd = (pre > 0.f) ? ct[r] : 0.f;
                        pd[r] = fmaf(dd, yw3[nt], pd[r]);
                    }
                }
                #pragma unroll
                for (int r = 0; r < 4; ++r) {
                    pq[r] = row_reduce16(pq[r]);
                    pf[r] = row_reduce16(pf[r]);
                    pd[r] = row_reduce16(pd[r]);
                }
                if (c == 0) {
                    float4_t q4, f4, d4;
                    #pragma unroll
                    for (int r = 0; r < 4; ++r) {
                        q4[r] = pq[r] + qb3; f4[r] = pf[r] + yb3; d4[r] = pd[r];
                    }
                    *(float4_t*)&xA[mt * 16 + g * 4] = q4;
                    *(float4_t*)&xB[mt * 16 + g * 4] = f4;
                    *(float4_t*)&xC[mt * 16 + g * 4] = d4;
                }
            }
            q  = xA[lane];
            Y  = xB[lane];
            dY = xC[lane];
        }
        // ======== end fused eval ========

        if (it > 0) {
            float resid = Y - (Y0 - 0.5f * q0 * q0 * DT + SIGMA * dY0 * dwprev);
            loss = fmaf(resid, resid, loss);
        }
        q0 = q; Y0 = Y; dY0 = dY; dwprev = dw;

        if (it < NSTEPS) {
            y = fmaf(SIGMA, dw, fmaf(q, DT, y));
            t += DT;
        }
    }

    // terminal: (YN - yN^2)^2
    float tm = Y0 - y * y;
    loss = fmaf(tm, tm, loss);

    #pragma unroll
    for (int off = 1; off < 64; off <<= 1) loss += __shfl_xor(loss, off, 64);
    if (lane == 0) rb[wv] = loss;
    __syncthreads();
    if (tid == 0) atomicAdd(out, (rb[0] + rb[1] + rb[2] + rb[3]) * (1.0f / (float)B_TOT));
}

extern "C" void kernel_launch(void* const* d_in, const int* in_sizes, int n_in,
                              void* d_out, int out_size, void* d_ws, size_t ws_size,
                              hipStream_t stream) {
    const float* dW  = (const float*)d_in[0];
    const float* y0i = (const float*)d_in[1];
    const float* Yw1 = (const float*)d_in[2];
    const float* Yb1 = (const float*)d_in[3];
    const float* Yw2 = (const float*)d_in[4];
    const float* Yb2 = (const float*)d_in[5];
    const float* Yw3 = (const float*)d_in[6];
    const float* Yb3 = (const float*)d_in[7];
    const float* Qw1 = (const float*)d_in[8];
    const float* Qb1 = (const float*)d_in[9];
    const float* Qw2 = (const float*)d_in[10];
    const float* Qb2 = (const float*)d_in[11];
    const float* Qw3 = (const float*)d_in[12];
    const float* Qb3 = (const float*)d_in[13];
    float* out = (float*)d_out;

    hipLaunchKernelGGL(zero_out_k, dim3(1), dim3(1), 0, stream, out);
    hipLaunchKernelGGL(fbsnn_k, dim3(B_TOT / 256), dim3(256), 0, stream,
                       dW, y0i, Yw1, Yb1, Yw2, Yb2, Yw3, Yb3,
                       Qw1, Qb1, Qw2, Qb2, Qw3, Qb3, out);
}